// Round 14
// baseline (406.659 us; speedup 1.0000x reference)
//
#include <hip/hip_runtime.h>
#include <cstdint>
#include <cstddef>

#define NB 8
#define NN 2048
#define MCV 32

using bf16x8 = __attribute__((ext_vector_type(8))) __bf16;
using f32x4  = __attribute__((ext_vector_type(4))) float;

__device__ __forceinline__ float bf2f(unsigned short u) {
  union { unsigned int i; float f; } v; v.i = ((unsigned int)u) << 16; return v.f;
}
__device__ __forceinline__ unsigned short f2bf(float f) {
  union { float f; unsigned int i; } v; v.f = f;
  unsigned int lsb = (v.i >> 16) & 1u;
  v.i += 0x7fffu + lsb;
  return (unsigned short)(v.i >> 16);
}
__device__ __forceinline__ float ld_in(const void* p, size_t idx, int mode) {
  return mode ? bf2f(((const unsigned short*)p)[idx]) : ((const float*)p)[idx];
}
// mode detect: cheb[0][0][0] == 1.0f (T0 = I). fp32 -> word 0x3F800000.
__device__ __forceinline__ int get_mode(const void* chebp) {
  return ((const unsigned int*)chebp)[0] != 0x3F800000u;
}

#define GLOAD16(gptr, lptr) \
  __builtin_amdgcn_global_load_lds((const __attribute__((address_space(1))) void*)(gptr), \
                                   (__attribute__((address_space(3))) void*)(lptr), 16, 0, 0)

// ---------------- canonicalize small inputs (+ optional cheb->bf16) ----------------
struct Seg { const void* src; void* dst; int count; int tobf; };
struct ConvArgs { Seg s[16]; };

__global__ void k_convert(ConvArgs a, const void* __restrict__ chebp) {
  const int mode = get_mode(chebp);
  const int stride = gridDim.x * blockDim.x;
  for (int si = 0; si < 16; ++si) {
    const Seg sg = a.s[si];
    for (int i = blockIdx.x * blockDim.x + threadIdx.x; i < sg.count; i += stride) {
      float v = ld_in(sg.src, i, mode);
      if (sg.tobf) ((unsigned short*)sg.dst)[i] = f2bf(v);
      else         ((float*)sg.dst)[i] = v;
    }
  }
}

// ---- Vs -> blocked bf16 [mt(8)][kt(32)][hf(2)][kc(8)][row(128)][8]; tail blocks do twr ----
__global__ void k_vsb(const void* __restrict__ vs, unsigned short* __restrict__ out,
                      const void* __restrict__ tw, unsigned short* __restrict__ twr,
                      const void* __restrict__ chebp) {
  const int mode = get_mode(chebp);
  const int idx = blockIdx.x * 256 + threadIdx.x;
  if (idx < NN * NN) {
    const int ke = idx & 7, row = (idx >> 3) & 127, kc = (idx >> 10) & 7;
    const int hf = (idx >> 13) & 1, kt = (idx >> 14) & 31, mt = idx >> 19;
    const int m = mt * 256 + hf * 128 + row, k = kt * 64 + kc * 8 + ke;
    out[idx] = f2bf(ld_in(vs, (size_t)m * NN + k, mode));
  } else {
    const int j = idx - NN * NN;
    if (j < 12288) {
      const int dt = j >> 12, rem = j & 4095, o = rem >> 6, c = rem & 63;
      twr[j] = f2bf(ld_in(tw, (size_t)o * 192 + c * 3 + dt, mode));
    }
  }
}

// ---------------- temporal attention (stages 1+2 fused): E[b][t][v] ----------------
__global__ __launch_bounds__(256) void k_temp1(const float* __restrict__ xf,
      const float* __restrict__ U1f, const float* __restrict__ U2f, const float* __restrict__ U3f,
      const float* __restrict__ bef, const float* __restrict__ Vef, float* __restrict__ E) {
  const int b = blockIdx.x;
  float accL[24], accG[24];
#pragma unroll
  for (int i = 0; i < 24; i++) { accL[i] = 0.f; accG[i] = 0.f; }
  const float u30 = U3f[0], u31 = U3f[1];
  for (int n = threadIdx.x; n < NN; n += 256) {
    const float* xp = xf + ((size_t)b * NN + n) * 24;
    const float u1 = U1f[n], u20 = U2f[n], u21 = U2f[NN + n];
#pragma unroll
    for (int t = 0; t < 12; t++) {
      float x0 = xp[t], x1 = xp[12 + t];
      accL[t * 2 + 0] += u1 * x0;
      accL[t * 2 + 1] += u1 * x1;
      float xs = u30 * x0 + u31 * x1;
      accG[t]      += u20 * xs;
      accG[12 + t] += u21 * xs;
    }
  }
#pragma unroll
  for (int i = 0; i < 24; i++) {
#pragma unroll
    for (int d = 32; d >= 1; d >>= 1) {
      accL[i] += __shfl_xor(accL[i], d, 64);
      accG[i] += __shfl_xor(accG[i], d, 64);
    }
  }
  __shared__ float red[4][48];
  __shared__ float L[48];
  __shared__ float s0[12][12], e1[12][12];
  const int lane = threadIdx.x & 63, wv = threadIdx.x >> 6;
  if (lane == 0) {
#pragma unroll
    for (int i = 0; i < 24; i++) { red[wv][i] = accL[i]; red[wv][24 + i] = accG[i]; }
  }
  __syncthreads();
  if (threadIdx.x < 48)
    L[threadIdx.x] = red[0][threadIdx.x] + red[1][threadIdx.x]
                   + red[2][threadIdx.x] + red[3][threadIdx.x];
  __syncthreads();
  const int tid = threadIdx.x;
  const int t = tid / 12, v = tid % 12;
  if (tid < 144) {
    float pr = L[t * 2 + 0] * L[24 + v] + L[t * 2 + 1] * L[36 + v] + bef[t * 12 + v];
    s0[t][v] = 1.f / (1.f + __expf(-pr));
  }
  __syncthreads();
  if (tid < 144) {
    float s = 0.f;
#pragma unroll
    for (int u = 0; u < 12; u++) s += Vef[t * 12 + u] * s0[u][v];
    e1[t][v] = s;
  }
  __syncthreads();
  if (tid < 144) {
    float mx = -1e30f;
#pragma unroll
    for (int u = 0; u < 12; u++) mx = fmaxf(mx, e1[u][v]);
    float sm = 0.f;
#pragma unroll
    for (int u = 0; u < 12; u++) sm += __expf(e1[u][v] - mx);
    E[b * 144 + t * 12 + v] = __expf(e1[t][v] - mx) / sm;
  }
}

// ---------------- x_TAt -> lhs_s[b][n][12], rhs_s[b][t][n] ----------------
__global__ __launch_bounds__(256) void k_xtat(const float* __restrict__ xf,
      const float* __restrict__ E, const float* __restrict__ W1f, const float* __restrict__ W2f,
      const float* __restrict__ W3f, float* __restrict__ lhs, float* __restrict__ rhsS) {
  const int b = blockIdx.y;
  const int n = blockIdx.x * 256 + threadIdx.x;
  __shared__ float Es[144];
  if (threadIdx.x < 144) Es[threadIdx.x] = E[b * 144 + threadIdx.x];
  __syncthreads();
  const float* xp = xf + ((size_t)b * NN + n) * 24;
  float xv[24];
#pragma unroll
  for (int i = 0; i < 24; i++) xv[i] = xp[i];
  float xT[24];
#pragma unroll
  for (int f = 0; f < 2; f++)
#pragma unroll
    for (int v = 0; v < 12; v++) {
      float s = 0.f;
#pragma unroll
      for (int u = 0; u < 12; u++) s += xv[f * 12 + u] * Es[u * 12 + v];
      xT[f * 12 + v] = s;
    }
  float a0 = 0.f, a1 = 0.f;
#pragma unroll
  for (int v = 0; v < 12; v++) { a0 += xT[v] * W1f[v]; a1 += xT[12 + v] * W1f[v]; }
  const float w30 = W3f[0], w31 = W3f[1];
  float* lp = lhs + ((size_t)b * NN + n) * 12;
#pragma unroll
  for (int t = 0; t < 12; t++) {
    lp[t] = a0 * W2f[t] + a1 * W2f[12 + t];
    rhsS[((size_t)b * 12 + t) * NN + n] = w30 * xT[t] + w31 * xT[12 + t];
  }
}

// ---- sigT blocked, LDS-transposed coalesced writeout ----
__global__ __launch_bounds__(256) void k_sig(const float* __restrict__ lhs,
      const float* __restrict__ rhsS, const void* __restrict__ bs,
      unsigned short* __restrict__ sigT, const void* __restrict__ chebp, int p0, int PL) {
  const int tid = threadIdx.x;
  const int n0 = blockIdx.x * 256;
  const int n = n0 + tid;
  const int pg0 = p0 + blockIdx.y * 16;
  const int mode = get_mode(chebp);
  __shared__ float rsl[8][12][16];
  __shared__ __align__(16) unsigned short sh[16][264];   // pad 264 -> bank-safe
  for (int i = tid; i < 1536; i += 256) {
    int b = i / 192, t = (i % 192) / 16, c = i % 16;
    rsl[b][t][c] = rhsS[((size_t)b * 12 + t) * NN + pg0 + c];
  }
  float bsv[16];
  if (mode) {
    const int4* bp = (const int4*)((const unsigned short*)bs + (size_t)n * NN + pg0);
    int4 q0 = bp[0], q1 = bp[1];
    const unsigned short* u0 = (const unsigned short*)&q0;
    const unsigned short* u1 = (const unsigned short*)&q1;
#pragma unroll
    for (int i = 0; i < 8; i++) { bsv[i] = bf2f(u0[i]); bsv[8 + i] = bf2f(u1[i]); }
  } else {
    const float4* fp = (const float4*)((const float*)bs + (size_t)n * NN + pg0);
#pragma unroll
    for (int q = 0; q < 4; q++) {
      float4 v = fp[q];
      bsv[q * 4 + 0] = v.x; bsv[q * 4 + 1] = v.y; bsv[q * 4 + 2] = v.z; bsv[q * 4 + 3] = v.w;
    }
  }
  __syncthreads();
  const int plbase = pg0 - p0;
  const size_t nbase = (size_t)(n0 >> 6) * 16384;
  for (int b = 0; b < 8; b++) {
    float lv[12];
    const float* lp = lhs + ((size_t)b * NN + n) * 12;
#pragma unroll
    for (int t = 0; t < 12; t++) lv[t] = lp[t];
#pragma unroll
    for (int pp = 0; pp < 16; pp++) {
      float acc = bsv[pp];
#pragma unroll
      for (int t = 0; t < 12; t++) acc += lv[t] * rsl[b][t][pp];
      float sg = 1.f / (1.f + __expf(-acc));
      sh[pp][tid] = f2bf(sg);
    }
    __syncthreads();
    const int gbase = b * PL + plbase;
    const size_t gt_off = (size_t)(gbase >> 8) * 524288 + (size_t)((gbase >> 7) & 1) * 8192
                        + (size_t)(gbase & 127) * 8 + nbase;
    for (int c = tid; c < 512; c += 256) {
      const int growL = c & 15, k3 = (c >> 4) & 7, n6 = c >> 7;
      int4 v = *(const int4*)&sh[growL][n6 * 64 + k3 * 8];
      *(int4*)&sigT[gt_off + (size_t)growL * 8 + (size_t)k3 * 1024 + (size_t)n6 * 16384] = v;
    }
    __syncthreads();
  }
}

// ---- S0 GEMM: 256x256 tile, 8-phase, 1 barrier/phase, counted vmcnt (round-11 schedule) ----
__global__ __launch_bounds__(512, 2) void k_gemm(const unsigned short* __restrict__ A,
      const unsigned short* __restrict__ Bm, unsigned short* __restrict__ C,
      float* __restrict__ pmax, float* __restrict__ psum,
      int PL, int plshift, int GP, int nwg) {
  __shared__ __align__(16) unsigned short lA[2][16384];
  __shared__ __align__(16) unsigned short lB[2][16384];
  const int id = blockIdx.x;
  const int cpx = nwg >> 3;
  const int sid = (id & 7) * cpx + (id >> 3);
  const int s = sid >> 4, w = sid & 15;
  const int mt = (s & 1) * 4 + (w & 3);
  const int pt = (s >> 1) * 4 + (w >> 2);
  const int tid = threadIdx.x;
  const int wv = tid >> 6, lane = tid & 63;
  const int fr = lane & 15, hi = lane >> 4;
  const int wr = wv >> 2, wc = wv & 3;
  const unsigned short* gA = A  + (size_t)mt * 524288;
  const unsigned short* gB = Bm + (size_t)pt * 524288;

  f32x4 acc[8][4] = {};
  bf16x8 af[8][2], bfr[4][2];

  // halftile h: kt=h>>2, part=h&3 (0=A-h0,1=A-h1,2=B-h0,3=B-h1); buf = kt&1
#define STAGE_H(h) do { \
    const int kt_ = (h) >> 2, part_ = (h) & 3, r_ = part_ & 1; \
    const unsigned short* gsrc_ = ((part_ < 2) ? gA : gB) + (size_t)kt_ * 16384 + r_ * 8192 + tid * 8; \
    unsigned short* ldst_ = ((part_ < 2) ? &lA[0][0] : &lB[0][0]) + (kt_ & 1) * 16384 + r_ * 8192 + wv * 512; \
    GLOAD16(gsrc_,        ldst_); \
    GLOAD16(gsrc_ + 4096, ldst_ + 4096); \
  } while (0)

#define READ_A03(bf) do { \
    _Pragma("unroll") for (int mi_ = 0; mi_ < 4; ++mi_) \
    _Pragma("unroll") for (int s2_ = 0; s2_ < 2; ++s2_) \
      af[mi_][s2_] = *(const bf16x8*)&lA[bf][wr * 8192 + (s2_ * 4 + hi) * 1024 + (mi_ * 16 + fr) * 8]; \
  } while (0)

#define READ_A47(bf) do { \
    _Pragma("unroll") for (int mi_ = 4; mi_ < 8; ++mi_) \
    _Pragma("unroll") for (int s2_ = 0; s2_ < 2; ++s2_) \
      af[mi_][s2_] = *(const bf16x8*)&lA[bf][wr * 8192 + (s2_ * 4 + hi) * 1024 + (mi_ * 16 + fr) * 8]; \
  } while (0)

#define READ_B01(bf) do { \
    _Pragma("unroll") for (int ni_ = 0; ni_ < 2; ++ni_) \
    _Pragma("unroll") for (int s2_ = 0; s2_ < 2; ++s2_) \
      bfr[ni_][s2_] = *(const bf16x8*)&lB[bf][(wc >> 1) * 8192 + (s2_ * 4 + hi) * 1024 \
                                             + ((wc & 1) * 64 + ni_ * 16 + fr) * 8]; \
  } while (0)

#define READ_B23(bf) do { \
    _Pragma("unroll") for (int ni_ = 2; ni_ < 4; ++ni_) \
    _Pragma("unroll") for (int s2_ = 0; s2_ < 2; ++s2_) \
      bfr[ni_][s2_] = *(const bf16x8*)&lB[bf][(wc >> 1) * 8192 + (s2_ * 4 + hi) * 1024 \
                                             + ((wc & 1) * 64 + ni_ * 16 + fr) * 8]; \
  } while (0)

#define MFMA_Q(mh, nh) do { \
    __builtin_amdgcn_s_setprio(1); \
    _Pragma("unroll") for (int s2_ = 0; s2_ < 2; ++s2_) \
    _Pragma("unroll") for (int mi_ = 0; mi_ < 4; ++mi_) \
    _Pragma("unroll") for (int ni_ = 0; ni_ < 2; ++ni_) \
      acc[(mh) * 4 + mi_][(nh) * 2 + ni_] = __builtin_amdgcn_mfma_f32_16x16x32_bf16( \
          af[(mh) * 4 + mi_][s2_], bfr[(nh) * 2 + ni_][s2_], acc[(mh) * 4 + mi_][(nh) * 2 + ni_], 0, 0, 0); \
    __builtin_amdgcn_s_setprio(0); \
  } while (0)

#define PH_BAR() __builtin_amdgcn_s_barrier()
#define PH_LGKM() asm volatile("s_waitcnt lgkmcnt(0)" ::: "memory")

  // prologue: tiles 0 and 1 fully staged; drain tile 0 (oldest 8 loads); barrier
  for (int h = 0; h < 8; ++h) STAGE_H(h);
  asm volatile("s_waitcnt vmcnt(8)" ::: "memory");
  PH_BAR();

  // Per-phase ledger (1 barrier per phase; every read-phase drains its own
  // lgkm before MFMA, hence before its end barrier -> stage-vs-read safe):
  //  ph1: rd A03,B01(buf0); stage A0(t1)      ph2: rd B23(buf0); stage A1(t1)
  //  ph3: rd A47(buf0);     stage B0(t0+2)    ph4: stage B1(t0+2); vmcnt(4)
  //  ph5-8 mirror on buf1.  Drain points land full t1 (ph4) / t0+2 (ph8).
#pragma unroll 1
  for (int i = 0; i < 16; ++i) {
    const int hb = 8 * i;
    const bool more = (i < 15);
    // ph1
    READ_A03(0); READ_B01(0);
    if (i > 0) STAGE_H(hb + 4);
    PH_LGKM();
    MFMA_Q(0, 0);
    PH_BAR();
    // ph2
    READ_B23(0);
    if (i > 0) STAGE_H(hb + 5);
    PH_LGKM();
    MFMA_Q(0, 1);
    PH_BAR();
    // ph3
    READ_A47(0);
    if (more) STAGE_H(hb + 10);
    PH_LGKM();
    MFMA_Q(1, 0);
    PH_BAR();
    // ph4
    if (more) STAGE_H(hb + 11);
    MFMA_Q(1, 1);
    if (more) asm volatile("s_waitcnt vmcnt(4)" ::: "memory");
    else      asm volatile("s_waitcnt vmcnt(0)" ::: "memory");
    PH_BAR();
    // ph5
    READ_A03(1); READ_B01(1);
    if (more) STAGE_H(hb + 8);
    PH_LGKM();
    MFMA_Q(0, 0);
    PH_BAR();
    // ph6
    READ_B23(1);
    if (more) STAGE_H(hb + 9);
    PH_LGKM();
    MFMA_Q(0, 1);
    PH_BAR();
    // ph7
    READ_A47(1);
    if (more) STAGE_H(hb + 14);
    PH_LGKM();
    MFMA_Q(1, 0);
    PH_BAR();
    // ph8
    if (more) STAGE_H(hb + 15);
    MFMA_Q(1, 1);
    if (more) asm volatile("s_waitcnt vmcnt(4)" ::: "memory");
    else      asm volatile("s_waitcnt vmcnt(0)" ::: "memory");
    PH_BAR();
  }
#undef STAGE_H
#undef READ_A03
#undef READ_A47
#undef READ_B01
#undef READ_B23
#undef MFMA_Q
#undef PH_BAR
#undef PH_LGKM

  const int m0 = mt * 256, gcol0 = pt * 256;
  const int plmask = PL - 1;
  // pass 1: column softmax stats (no stores)
#pragma unroll
  for (int ni = 0; ni < 4; ++ni) {
    float lmax = -1e30f;
    float vv[8][4];
#pragma unroll
    for (int mi = 0; mi < 8; ++mi)
#pragma unroll
      for (int r = 0; r < 4; r++) {
        float x = bf2f(f2bf(acc[mi][ni][r]));
        vv[mi][r] = x;
        lmax = fmaxf(lmax, x);
      }
    float lsum = 0.f;
#pragma unroll
    for (int mi = 0; mi < 8; ++mi)
#pragma unroll
      for (int r = 0; r < 4; r++) lsum += __expf(vv[mi][r] - lmax);
#pragma unroll
    for (int d = 16; d <= 32; d <<= 1) {
      float omax = __shfl_xor(lmax, d, 64);
      float osum = __shfl_xor(lsum, d, 64);
      float nm = fmaxf(lmax, omax);
      lsum = lsum * __expf(lmax - nm) + osum * __expf(omax - nm);
      lmax = nm;
    }
    if (hi == 0) {
      const int part = mt * 2 + wr;
      const int g = gcol0 + wc * 64 + ni * 16 + lane;
      pmax[(size_t)part * GP + g] = lmax;
      psum[(size_t)part * GP + g] = lsum;
    }
  }
  // pass 2: C stores, same-line halves adjacent in time (L2 write-merge)
#pragma unroll
  for (int mi = 0; mi < 8; ++mi) {
#pragma unroll
    for (int r = 0; r < 4; r++) {
      const int mrow = m0 + wr * 128 + mi * 16 + hi * 4 + r;
#pragma unroll
      for (int ni = 0; ni < 4; ++ni) {
        const int g = gcol0 + wc * 64 + ni * 16 + fr;
        const int b = g >> plshift, pl = g & plmask;
        C[((size_t)b * NN + mrow) * PL + pl] = f2bf(acc[mi][ni][r]);
      }
    }
  }
}

// ---- cheb partials: xf slice LDS-staged, unroll-4 m loop ----
__global__ __launch_bounds__(256) void k_cheb(const unsigned short* __restrict__ S0c,
        const void* __restrict__ cheb, const unsigned short* __restrict__ cbf, int use_cbf,
        const float* __restrict__ xf, const float* __restrict__ pmax, const float* __restrict__ psum,
        unsigned short* __restrict__ part, int p0, int PL, int mspan, int GP) {
  const int b = blockIdx.z, mc = blockIdx.y;
  const int pl = blockIdx.x * 256 + threadIdx.x;
  const int n = p0 + pl;
  const int mode = get_mode(cheb);
  const int g = b * PL + pl;
  __shared__ __align__(16) float xsh[64][24];   // mspan == 64
  const int m0 = mc * mspan;
  {
    const float* src = xf + ((size_t)b * NN + m0) * 24;
    for (int i = threadIdx.x; i < 64 * 24 / 4; i += 256) {
      *(f32x4*)&((float*)xsh)[i * 4] = *(const f32x4*)&src[i * 4];
    }
  }
  float mx = -1e30f;
#pragma unroll
  for (int c = 0; c < 16; c++) mx = fmaxf(mx, pmax[(size_t)c * GP + g]);
  float sm = 0.f;
#pragma unroll
  for (int c = 0; c < 16; c++) sm += psum[(size_t)c * GP + g] * __expf(pmax[(size_t)c * GP + g] - mx);
  const float inv = 1.f / sm;
  float acc[3][24];
#pragma unroll
  for (int k = 0; k < 3; k++)
#pragma unroll
    for (int j = 0; j < 24; j++) acc[k][j] = 0.f;
  __syncthreads();
  const unsigned short* s0p = S0c + (size_t)b * NN * PL + pl + (size_t)m0 * PL;
  if (use_cbf || mode) {
    const unsigned short* cb0 = (use_cbf ? cbf : (const unsigned short*)cheb) + n + (size_t)m0 * NN;
    const unsigned short* cb1 = cb0 + (size_t)NN * NN;
    const unsigned short* cb2 = cb1 + (size_t)NN * NN;
#pragma unroll 4
    for (int mi = 0; mi < 64; ++mi) {
      float w = __expf(bf2f(s0p[(size_t)mi * PL]) - mx) * inv;
      float w0 = w * bf2f(cb0[(size_t)mi * NN]);
      float w1 = w * bf2f(cb1[(size_t)mi * NN]);
      float w2 = w * bf2f(cb2[(size_t)mi * NN]);
      const f32x4* xp = (const f32x4*)&xsh[mi][0];
#pragma unroll
      for (int q = 0; q < 6; q++) {
        f32x4 xv = xp[q];
#pragma unroll
        for (int e = 0; e < 4; e++) {
          int j = q * 4 + e;
          acc[0][j] += w0 * xv[e];
          acc[1][j] += w1 * xv[e];
          acc[2][j] += w2 * xv[e];
        }
      }
    }
  } else {
    const float* cb0 = (const float*)cheb + n + (size_t)m0 * NN;
    const float* cb1 = cb0 + (size_t)NN * NN;
    const float* cb2 = cb1 + (size_t)NN * NN;
#pragma unroll 4
    for (int mi = 0; mi < 64; ++mi) {
      float w = __expf(bf2f(s0p[(size_t)mi * PL]) - mx) * inv;
      float w0 = w * cb0[(size_t)mi * NN];
      float w1 = w * cb1[(size_t)mi * NN];
      float w2 = w * cb2[(size_t)mi * NN];
      const f32x4* xp = (const f32x4*)&xsh[mi][0];
#pragma unroll
      for (int q = 0; q < 6; q++) {
        f32x4 xv = xp[q];
#pragma unroll
        for (int e = 0; e < 4; e++) {
          int j = q * 4 + e;
          acc[0][j] += w0 * xv[e];
          acc[1][j] += w1 * xv[e];
          acc[2][j] += w2 * xv[e];
        }
      }
    }
  }
  unsigned short* pp = part + ((size_t)(mc * 8 + b) * 72) * PL + pl;
#pragma unroll
  for (int k = 0; k < 3; k++)
#pragma unroll
    for (int j = 0; j < 24; j++) pp[(size_t)(k * 24 + j) * PL] = f2bf(acc[k][j]);
}

__global__ void k_chebred(const unsigned short* __restrict__ part, float* __restrict__ rhsC,
                          int p0, int PL) {
  const int idx = blockIdx.x * 256 + threadIdx.x;
  if (idx >= 8 * 72 * PL) return;
  const int pl = idx % PL;
  const int r = idx / PL;
  const int j = r % 72, b = r / 72;
  float s = 0.f;
  for (int mc = 0; mc < MCV; ++mc)
    s += bf2f(part[((size_t)(mc * 8 + b) * 72 + j) * PL + pl]);
  rhsC[((size_t)b * NN + p0 + pl) * 72 + j] = s;
}

// ---- final: Theta mix + relu + tconv via MFMA + res(1x1) + relu + LN(64) ----
__global__ __launch_bounds__(256) void k_final(const float* __restrict__ rhsC,
      const float* __restrict__ Thf, const unsigned short* __restrict__ twr,
      const float* __restrict__ tbf, const float* __restrict__ rwf, const float* __restrict__ rbf,
      const float* __restrict__ lngf, const float* __restrict__ lnbf,
      const float* __restrict__ xf, void* __restrict__ out, const void* __restrict__ chebp) {
  const int mode = get_mode(chebp);
  __shared__ __align__(16) unsigned short ltw[192 * 72];
  __shared__ __align__(16) unsigned short gT[4][18][72];
  __shared__ float rl[4][72];
  __shared__ float prm[6][64];
  const int tid = threadIdx.x;
  const int wv = tid >> 6, lane = tid & 63;
  const size_t bn = (size_t)blockIdx.x * 4 + wv;

  for (int i = tid; i < 1536; i += 256) {
    const int row = i >> 3, cseg = (i & 7) * 8;
    *(bf16x8*)&ltw[row * 72 + cseg] = *(const bf16x8*)&twr[row * 64 + cseg];
  }
  if (tid < 64) {
    prm[0][tid] = tbf[tid] + rbf[tid];
    prm[1][tid] = rwf[tid * 2];
    prm[2][tid] = rwf[tid * 2 + 1];
    prm[3][tid] = lngf[tid];
    prm[4][tid] = lnbf[tid];
  }
  for (int i = lane; i < 648; i += 64) ((unsigned int*)&gT[wv][0][0])[i] = 0u;
  {
    const float* rp = rhsC + bn * 72;
    rl[wv][lane] = rp[lane];
    if (lane < 8) rl[wv][64 + lane] = rp[64 + lane];
  }
  __syncthreads();
  {
    const int c = lane;
    float th[6];
#pragma unroll
    for (int kf = 0; kf < 6; kf++) th[kf] = Thf[kf * 64 + c];
#pragma unroll
    for (int t = 0; t < 12; t++) {
      float s = 0.f;
#pragma unroll
      for (int kf = 0; kf < 6; kf++) s += rl[wv][kf * 12 + t] * th[kf];
      gT[wv][1 + t][c] = f2bf(fmaxf(s, 0.f));
    }
  }
  __syncthreads();
  const int fr = lane & 15, hi = lane >> 4;
  f32x4 acc4[4] = {};
#pragma unroll
  for (int dt = 0; dt < 3; dt++)
#pragma unroll
    for (int ks = 0; ks < 2; ks++) {
      bf16x8 bfrag = *(const bf16x8*)&gT[wv][fr + dt][ks * 32 + hi * 8];
#pragma unroll
      for (int ot = 0; ot < 4; ot++) {
        bf16x8 afrag = *(const bf16x8*)&ltw[(dt * 64 + ot * 16 + fr) * 72 + ks * 32 + hi * 8];
        acc4[ot] = __builtin_amdgcn_mfma_f32_16x16x32_bf16(afrag, bfrag, acc4[ot], 0, 0, 0);
      }
    }
  const int t = fr;
  const int tc = t < 12 ? t : 11;
  const float x0 = xf[bn * 24 + tc], x1 = xf[bn * 24 + 12 + tc];
  float vals[4][4];
  float sum = 0.f, sumsq = 0.f;
#pragma unroll
  for (int ot = 0; ot < 4; ot++) {
    f32x4 rbt4 = *(const f32x4*)&prm[0][ot * 16 + hi * 4];
    f32x4 rw04 = *(const f32x4*)&prm[1][ot * 16 + hi * 4];
    f32x4 rw14 = *(const f32x4*)&prm[2][ot * 16 + hi * 4];
#pragma unroll
    for (int r = 0; r < 4; r++) {
      float v = acc4[ot][r] + rbt4[r] + rw04[r] * x0 + rw14[r] * x1;
      v = fmaxf(v, 0.f);
      vals[ot][r] = v;
      sum += v; sumsq += v * v;
    }
  }
  sum   += __shfl_xor(sum, 16, 64);
  sumsq += __shfl_xor(sumsq, 16, 64);
  sum   += __shfl_xor(sum, 32, 64);
  sumsq += __shfl_xor(sumsq, 32, 64);
  const float mu = sum * (1.f / 64.f);
  const float var = sumsq * (1.f / 64.f) - mu * mu;
  const float rs = rsqrtf(var + 1e-5f);
  if (t < 12) {
#pragma unroll
    for (int ot = 0; ot < 4; ot++) {
      f32x4 lg4 = *(const f32x4*)&prm[3][ot * 16 + hi * 4];
      f32x4 lb4 = *(const f32x4*)&prm[4][ot * 16 + hi * 4];
#pragma unroll
      for (int r = 0; r < 4; r++) {
        const int o = ot * 16 + hi * 4 + r;
        float y = (vals[ot][r] - mu) * rs * lg4[r] + lb4[r];
        if (mode) ((unsigned short*)out)[bn * 768 + o * 12 + t] = f2bf(y);
        else      ((float*)out)[bn * 768 + o * 12 + t] = y;
      }
    }
  }
}

// ---------------- workspace plan ----------------
struct Plan {
  size_t o_xf, o_Th, o_U1, o_U2, o_U3, o_be, o_Ve, o_W1, o_W2, o_W3,
         o_twr, o_tb, o_rw, o_rb, o_lg, o_lb, o_Vs,
         o_E, o_lhs, o_rhsS, o_rhsC,
         o_R1, o_S0, o_pmax, o_psum, o_cbf;
  size_t total;
};

static Plan make_plan(int PL, int cbf) {
  Plan p; size_t off = 0;
  auto al = [&](size_t b) { size_t r = off; off += (b + 255) & ~(size_t)255; return r; };
  const int GP = 8 * PL;
  p.o_xf   = al((size_t)NB * NN * 24 * 4);
  p.o_Th   = al(384 * 4);
  p.o_U1   = al(2048 * 4);
  p.o_U2   = al(4096 * 4);
  p.o_U3   = al(2 * 4);
  p.o_be   = al(144 * 4);
  p.o_Ve   = al(144 * 4);
  p.o_W1   = al(12 * 4);
  p.o_W2   = al(24 * 4);
  p.o_W3   = al(2 * 4);
  p.o_twr  = al(12288 * 2);
  p.o_tb   = al(64 * 4);
  p.o_rw   = al(128 * 4);
  p.o_rb   = al(64 * 4);
  p.o_lg   = al(64 * 4);
  p.o_lb   = al(64 * 4);
  p.o_Vs   = al((size_t)NN * NN * 2);
  p.o_E    = al(NB * 144 * 4);
  p.o_lhs  = al((size_t)NB * NN * 12 * 4);
  p.o_rhsS = al((size_t)NB * 12 * NN * 4);
  p.o_rhsC = al((size_t)NB * NN * 72 * 4);
  // union region: sigT (32768*PL) aliased with bf16 part (MCV*8*72*2 = 36864*PL)
  p.o_R1   = al((size_t)36864 * PL);
  p.o_S0   = al((size_t)NB * NN * PL * 2);
  p.o_pmax = al((size_t)16 * GP * 4);
  p.o_psum = al((size_t)16 * GP * 4);
  p.o_cbf  = cbf ? al((size_t)3 * NN * NN * 2) : 0;
  p.total = off;
  return p;
}

extern "C" void kernel_launch(void* const* d_in, const int* in_sizes, int n_in,
                              void* d_out, int out_size, void* d_ws, size_t ws_size,
                              hipStream_t stream) {
  (void)in_sizes; (void)n_in; (void)out_size;
  char* ws = (char*)d_ws;

  int PL, use_cbf;
  if      (make_plan(1024, 1).total <= ws_size) { PL = 1024; use_cbf = 1; }
  else if (make_plan(1024, 0).total <= ws_size) { PL = 1024; use_cbf = 0; }
  else if (make_plan(512, 1).total  <= ws_size) { PL = 512;  use_cbf = 1; }
  else                                          { PL = 512;  use_cbf = 0; }
  const Plan P = make_plan(PL, use_cbf);
  const int GP = 8 * PL;
  const int plshift = (PL == 512) ? 9 : 10;
  const int mspan = NN / MCV;
  const void* chebp = d_in[1];

  float* xf   = (float*)(ws + P.o_xf);
  float* Ebuf = (float*)(ws + P.o_E);
  float* lhs  = (float*)(ws + P.o_lhs);
  float* rhsS = (float*)(ws + P.o_rhsS);
  float* rhsC = (float*)(ws + P.o_rhsC);
  unsigned short* sigT = (unsigned short*)(ws + P.o_R1);
  unsigned short* part = (unsigned short*)(ws + P.o_R1);
  unsigned short* S0c  = (unsigned short*)(ws + P.o_S0);
  float* pmax = (float*)(ws + P.o_pmax);
  float* psum = (float*)(ws + P.o_psum);
  unsigned short* cbfp = use_cbf ? (unsigned short*)(ws + P.o_cbf)
                                 : (unsigned short*)d_in[1];

  ConvArgs ca;
  auto seg = [&](int i, int di, size_t o, int count, int tobf) {
    ca.s[i].src = d_in[di]; ca.s[i].dst = (void*)(ws + o); ca.s[i].count = count; ca.s[i].tobf = tobf;
  };
  seg(0, 0, P.o_xf, 393216, 0);
  seg(1, 2, P.o_Th, 384, 0);
  seg(2, 3, P.o_U1, 2048, 0);
  seg(3, 4, P.o_U2, 4096, 0);
  seg(4, 5, P.o_U3, 2, 0);
  seg(5, 6, P.o_be, 144, 0);
  seg(6, 7, P.o_Ve, 144, 0);
  seg(7, 8, P.o_W1, 12, 0);
  seg(8, 9, P.o_W2, 24, 0);
  seg(9, 10, P.o_W3, 2, 0);
  seg(10, 14, P.o_tb, 64, 0);
  seg(11, 15, P.o_rw, 128, 0);
  seg(12, 16, P.o_rb, 64, 0);
  seg(13, 17, P.o_lg, 64, 0);
  seg(14, 18, P.o_lb, 64, 0);
  seg(15, 1, P.o_cbf, use_cbf ? 3 * NN * NN : 0, 1);
  k_convert<<<1024, 256, 0, stream>>>(ca, chebp);
  k_vsb<<<(NN * NN + 12288 + 255) / 256, 256, 0, stream>>>(d_in[12],
      (unsigned short*)(ws + P.o_Vs), d_in[13], (unsigned short*)(ws + P.o_twr), chebp);

  k_temp1<<<NB, 256, 0, stream>>>(xf, (float*)(ws + P.o_U1), (float*)(ws + P.o_U2),
                                  (float*)(ws + P.o_U3), (float*)(ws + P.o_be),
                                  (float*)(ws + P.o_Ve), Ebuf);
  k_xtat<<<dim3(8, NB), 256, 0, stream>>>(xf, Ebuf, (float*)(ws + P.o_W1), (float*)(ws + P.o_W2),
                                          (float*)(ws + P.o_W3), lhs, rhsS);

  const int nwg = 8 * (GP / 256);
  for (int p0 = 0; p0 < NN; p0 += PL) {
    k_sig<<<dim3(8, PL / 16), 256, 0, stream>>>(lhs, rhsS, d_in[11], sigT, chebp, p0, PL);
    k_gemm<<<nwg, 512, 0, stream>>>((unsigned short*)(ws + P.o_Vs), sigT, S0c,
                                    pmax, psum, PL, plshift, GP, nwg);
    k_cheb<<<dim3(PL / 256, MCV, NB), 256, 0, stream>>>(S0c, d_in[1], cbfp, use_cbf,
                                                        xf, pmax, psum, part, p0, PL, mspan, GP);
    k_chebred<<<(8 * 72 * PL + 255) / 256, 256, 0, stream>>>(part, rhsC, p0, PL);
  }

  k_final<<<NB * NN / 4, 256, 0, stream>>>(rhsC, (float*)(ws + P.o_Th),
      (unsigned short*)(ws + P.o_twr), (float*)(ws + P.o_tb), (float*)(ws + P.o_rw),
      (float*)(ws + P.o_rb), (float*)(ws + P.o_lg), (float*)(ws + P.o_lb), xf, d_out, chebp);
}

// Round 15
// 347.345 us; speedup vs baseline: 1.1708x; 1.1708x over previous
//
#include <hip/hip_runtime.h>
#include <cstdint>
#include <cstddef>

#define NB 8
#define NN 2048
#define MCV 32

using bf16x8 = __attribute__((ext_vector_type(8))) __bf16;
using f32x4  = __attribute__((ext_vector_type(4))) float;

__device__ __forceinline__ float bf2f(unsigned short u) {
  union { unsigned int i; float f; } v; v.i = ((unsigned int)u) << 16; return v.f;
}
__device__ __forceinline__ unsigned short f2bf(float f) {
  union { float f; unsigned int i; } v; v.f = f;
  unsigned int lsb = (v.i >> 16) & 1u;
  v.i += 0x7fffu + lsb;
  return (unsigned short)(v.i >> 16);
}
__device__ __forceinline__ float ld_in(const void* p, size_t idx, int mode) {
  return mode ? bf2f(((const unsigned short*)p)[idx]) : ((const float*)p)[idx];
}
// mode detect: cheb[0][0][0] == 1.0f (T0 = I). fp32 -> word 0x3F800000.
__device__ __forceinline__ int get_mode(const void* chebp) {
  return ((const unsigned int*)chebp)[0] != 0x3F800000u;
}

#define GLOAD16(gptr, lptr) \
  __builtin_amdgcn_global_load_lds((const __attribute__((address_space(1))) void*)(gptr), \
                                   (__attribute__((address_space(3))) void*)(lptr), 16, 0, 0)

// ---------------- canonicalize small inputs (+ optional cheb->bf16) ----------------
struct Seg { const void* src; void* dst; int count; int tobf; };
struct ConvArgs { Seg s[16]; };

__global__ void k_convert(ConvArgs a, const void* __restrict__ chebp) {
  const int mode = get_mode(chebp);
  const int stride = gridDim.x * blockDim.x;
  for (int si = 0; si < 16; ++si) {
    const Seg sg = a.s[si];
    for (int i = blockIdx.x * blockDim.x + threadIdx.x; i < sg.count; i += stride) {
      float v = ld_in(sg.src, i, mode);
      if (sg.tobf) ((unsigned short*)sg.dst)[i] = f2bf(v);
      else         ((float*)sg.dst)[i] = v;
    }
  }
}

// ---- Vs -> blocked bf16 [mt(8)][kt(32)][hf(2)][kc(8)][row(128)][8]; tail blocks do twr ----
__global__ void k_vsb(const void* __restrict__ vs, unsigned short* __restrict__ out,
                      const void* __restrict__ tw, unsigned short* __restrict__ twr,
                      const void* __restrict__ chebp) {
  const int mode = get_mode(chebp);
  const int idx = blockIdx.x * 256 + threadIdx.x;
  if (idx < NN * NN) {
    const int ke = idx & 7, row = (idx >> 3) & 127, kc = (idx >> 10) & 7;
    const int hf = (idx >> 13) & 1, kt = (idx >> 14) & 31, mt = idx >> 19;
    const int m = mt * 256 + hf * 128 + row, k = kt * 64 + kc * 8 + ke;
    out[idx] = f2bf(ld_in(vs, (size_t)m * NN + k, mode));
  } else {
    const int j = idx - NN * NN;
    if (j < 12288) {
      const int dt = j >> 12, rem = j & 4095, o = rem >> 6, c = rem & 63;
      twr[j] = f2bf(ld_in(tw, (size_t)o * 192 + c * 3 + dt, mode));
    }
  }
}

// ---------------- temporal attention (stages 1+2 fused): E[b][t][v] ----------------
__global__ __launch_bounds__(256) void k_temp1(const float* __restrict__ xf,
      const float* __restrict__ U1f, const float* __restrict__ U2f, const float* __restrict__ U3f,
      const float* __restrict__ bef, const float* __restrict__ Vef, float* __restrict__ E) {
  const int b = blockIdx.x;
  float accL[24], accG[24];
#pragma unroll
  for (int i = 0; i < 24; i++) { accL[i] = 0.f; accG[i] = 0.f; }
  const float u30 = U3f[0], u31 = U3f[1];
  for (int n = threadIdx.x; n < NN; n += 256) {
    const float* xp = xf + ((size_t)b * NN + n) * 24;
    const float u1 = U1f[n], u20 = U2f[n], u21 = U2f[NN + n];
#pragma unroll
    for (int t = 0; t < 12; t++) {
      float x0 = xp[t], x1 = xp[12 + t];
      accL[t * 2 + 0] += u1 * x0;
      accL[t * 2 + 1] += u1 * x1;
      float xs = u30 * x0 + u31 * x1;
      accG[t]      += u20 * xs;
      accG[12 + t] += u21 * xs;
    }
  }
#pragma unroll
  for (int i = 0; i < 24; i++) {
#pragma unroll
    for (int d = 32; d >= 1; d >>= 1) {
      accL[i] += __shfl_xor(accL[i], d, 64);
      accG[i] += __shfl_xor(accG[i], d, 64);
    }
  }
  __shared__ float red[4][48];
  __shared__ float L[48];
  __shared__ float s0[12][12], e1[12][12];
  const int lane = threadIdx.x & 63, wv = threadIdx.x >> 6;
  if (lane == 0) {
#pragma unroll
    for (int i = 0; i < 24; i++) { red[wv][i] = accL[i]; red[wv][24 + i] = accG[i]; }
  }
  __syncthreads();
  if (threadIdx.x < 48)
    L[threadIdx.x] = red[0][threadIdx.x] + red[1][threadIdx.x]
                   + red[2][threadIdx.x] + red[3][threadIdx.x];
  __syncthreads();
  const int tid = threadIdx.x;
  const int t = tid / 12, v = tid % 12;
  if (tid < 144) {
    float pr = L[t * 2 + 0] * L[24 + v] + L[t * 2 + 1] * L[36 + v] + bef[t * 12 + v];
    s0[t][v] = 1.f / (1.f + __expf(-pr));
  }
  __syncthreads();
  if (tid < 144) {
    float s = 0.f;
#pragma unroll
    for (int u = 0; u < 12; u++) s += Vef[t * 12 + u] * s0[u][v];
    e1[t][v] = s;
  }
  __syncthreads();
  if (tid < 144) {
    float mx = -1e30f;
#pragma unroll
    for (int u = 0; u < 12; u++) mx = fmaxf(mx, e1[u][v]);
    float sm = 0.f;
#pragma unroll
    for (int u = 0; u < 12; u++) sm += __expf(e1[u][v] - mx);
    E[b * 144 + t * 12 + v] = __expf(e1[t][v] - mx) / sm;
  }
}

// ---------------- x_TAt -> lhs_s[b][n][12], rhs_s[b][t][n] ----------------
__global__ __launch_bounds__(256) void k_xtat(const float* __restrict__ xf,
      const float* __restrict__ E, const float* __restrict__ W1f, const float* __restrict__ W2f,
      const float* __restrict__ W3f, float* __restrict__ lhs, float* __restrict__ rhsS) {
  const int b = blockIdx.y;
  const int n = blockIdx.x * 256 + threadIdx.x;
  __shared__ float Es[144];
  if (threadIdx.x < 144) Es[threadIdx.x] = E[b * 144 + threadIdx.x];
  __syncthreads();
  const float* xp = xf + ((size_t)b * NN + n) * 24;
  float xv[24];
#pragma unroll
  for (int i = 0; i < 24; i++) xv[i] = xp[i];
  float xT[24];
#pragma unroll
  for (int f = 0; f < 2; f++)
#pragma unroll
    for (int v = 0; v < 12; v++) {
      float s = 0.f;
#pragma unroll
      for (int u = 0; u < 12; u++) s += xv[f * 12 + u] * Es[u * 12 + v];
      xT[f * 12 + v] = s;
    }
  float a0 = 0.f, a1 = 0.f;
#pragma unroll
  for (int v = 0; v < 12; v++) { a0 += xT[v] * W1f[v]; a1 += xT[12 + v] * W1f[v]; }
  const float w30 = W3f[0], w31 = W3f[1];
  float* lp = lhs + ((size_t)b * NN + n) * 12;
#pragma unroll
  for (int t = 0; t < 12; t++) {
    lp[t] = a0 * W2f[t] + a1 * W2f[12 + t];
    rhsS[((size_t)b * 12 + t) * NN + n] = w30 * xT[t] + w31 * xT[12 + t];
  }
}

// ---- sigT blocked, LDS-transposed coalesced writeout ----
__global__ __launch_bounds__(256) void k_sig(const float* __restrict__ lhs,
      const float* __restrict__ rhsS, const void* __restrict__ bs,
      unsigned short* __restrict__ sigT, const void* __restrict__ chebp, int p0, int PL) {
  const int tid = threadIdx.x;
  const int n0 = blockIdx.x * 256;
  const int n = n0 + tid;
  const int pg0 = p0 + blockIdx.y * 16;
  const int mode = get_mode(chebp);
  __shared__ float rsl[8][12][16];
  __shared__ __align__(16) unsigned short sh[16][264];   // pad 264 -> bank-safe
  for (int i = tid; i < 1536; i += 256) {
    int b = i / 192, t = (i % 192) / 16, c = i % 16;
    rsl[b][t][c] = rhsS[((size_t)b * 12 + t) * NN + pg0 + c];
  }
  float bsv[16];
  if (mode) {
    const int4* bp = (const int4*)((const unsigned short*)bs + (size_t)n * NN + pg0);
    int4 q0 = bp[0], q1 = bp[1];
    const unsigned short* u0 = (const unsigned short*)&q0;
    const unsigned short* u1 = (const unsigned short*)&q1;
#pragma unroll
    for (int i = 0; i < 8; i++) { bsv[i] = bf2f(u0[i]); bsv[8 + i] = bf2f(u1[i]); }
  } else {
    const float4* fp = (const float4*)((const float*)bs + (size_t)n * NN + pg0);
#pragma unroll
    for (int q = 0; q < 4; q++) {
      float4 v = fp[q];
      bsv[q * 4 + 0] = v.x; bsv[q * 4 + 1] = v.y; bsv[q * 4 + 2] = v.z; bsv[q * 4 + 3] = v.w;
    }
  }
  __syncthreads();
  const int plbase = pg0 - p0;
  const size_t nbase = (size_t)(n0 >> 6) * 16384;
  for (int b = 0; b < 8; b++) {
    float lv[12];
    const float* lp = lhs + ((size_t)b * NN + n) * 12;
#pragma unroll
    for (int t = 0; t < 12; t++) lv[t] = lp[t];
#pragma unroll
    for (int pp = 0; pp < 16; pp++) {
      float acc = bsv[pp];
#pragma unroll
      for (int t = 0; t < 12; t++) acc += lv[t] * rsl[b][t][pp];
      float sg = 1.f / (1.f + __expf(-acc));
      sh[pp][tid] = f2bf(sg);
    }
    __syncthreads();
    const int gbase = b * PL + plbase;
    const size_t gt_off = (size_t)(gbase >> 8) * 524288 + (size_t)((gbase >> 7) & 1) * 8192
                        + (size_t)(gbase & 127) * 8 + nbase;
    for (int c = tid; c < 512; c += 256) {
      const int growL = c & 15, k3 = (c >> 4) & 7, n6 = c >> 7;
      int4 v = *(const int4*)&sh[growL][n6 * 64 + k3 * 8];
      *(int4*)&sigT[gt_off + (size_t)growL * 8 + (size_t)k3 * 1024 + (size_t)n6 * 16384] = v;
    }
    __syncthreads();
  }
}

// ---- S0 GEMM: 256x256 tile, 8-phase, 1 barrier/phase, counted vmcnt (round-11 schedule) ----
__global__ __launch_bounds__(512, 2) void k_gemm(const unsigned short* __restrict__ A,
      const unsigned short* __restrict__ Bm, unsigned short* __restrict__ C,
      float* __restrict__ pmax, float* __restrict__ psum,
      int PL, int plshift, int GP, int nwg) {
  __shared__ __align__(16) unsigned short lA[2][16384];
  __shared__ __align__(16) unsigned short lB[2][16384];
  const int id = blockIdx.x;
  const int cpx = nwg >> 3;
  const int sid = (id & 7) * cpx + (id >> 3);
  const int s = sid >> 4, w = sid & 15;
  const int mt = (s & 1) * 4 + (w & 3);
  const int pt = (s >> 1) * 4 + (w >> 2);
  const int tid = threadIdx.x;
  const int wv = tid >> 6, lane = tid & 63;
  const int fr = lane & 15, hi = lane >> 4;
  const int wr = wv >> 2, wc = wv & 3;
  const unsigned short* gA = A  + (size_t)mt * 524288;
  const unsigned short* gB = Bm + (size_t)pt * 524288;

  f32x4 acc[8][4] = {};
  bf16x8 af[8][2], bfr[4][2];

  // halftile h: kt=h>>2, part=h&3 (0=A-h0,1=A-h1,2=B-h0,3=B-h1); buf = kt&1
#define STAGE_H(h) do { \
    const int kt_ = (h) >> 2, part_ = (h) & 3, r_ = part_ & 1; \
    const unsigned short* gsrc_ = ((part_ < 2) ? gA : gB) + (size_t)kt_ * 16384 + r_ * 8192 + tid * 8; \
    unsigned short* ldst_ = ((part_ < 2) ? &lA[0][0] : &lB[0][0]) + (kt_ & 1) * 16384 + r_ * 8192 + wv * 512; \
    GLOAD16(gsrc_,        ldst_); \
    GLOAD16(gsrc_ + 4096, ldst_ + 4096); \
  } while (0)

#define READ_A03(bf) do { \
    _Pragma("unroll") for (int mi_ = 0; mi_ < 4; ++mi_) \
    _Pragma("unroll") for (int s2_ = 0; s2_ < 2; ++s2_) \
      af[mi_][s2_] = *(const bf16x8*)&lA[bf][wr * 8192 + (s2_ * 4 + hi) * 1024 + (mi_ * 16 + fr) * 8]; \
  } while (0)

#define READ_A47(bf) do { \
    _Pragma("unroll") for (int mi_ = 4; mi_ < 8; ++mi_) \
    _Pragma("unroll") for (int s2_ = 0; s2_ < 2; ++s2_) \
      af[mi_][s2_] = *(const bf16x8*)&lA[bf][wr * 8192 + (s2_ * 4 + hi) * 1024 + (mi_ * 16 + fr) * 8]; \
  } while (0)

#define READ_B01(bf) do { \
    _Pragma("unroll") for (int ni_ = 0; ni_ < 2; ++ni_) \
    _Pragma("unroll") for (int s2_ = 0; s2_ < 2; ++s2_) \
      bfr[ni_][s2_] = *(const bf16x8*)&lB[bf][(wc >> 1) * 8192 + (s2_ * 4 + hi) * 1024 \
                                             + ((wc & 1) * 64 + ni_ * 16 + fr) * 8]; \
  } while (0)

#define READ_B23(bf) do { \
    _Pragma("unroll") for (int ni_ = 2; ni_ < 4; ++ni_) \
    _Pragma("unroll") for (int s2_ = 0; s2_ < 2; ++s2_) \
      bfr[ni_][s2_] = *(const bf16x8*)&lB[bf][(wc >> 1) * 8192 + (s2_ * 4 + hi) * 1024 \
                                             + ((wc & 1) * 64 + ni_ * 16 + fr) * 8]; \
  } while (0)

#define MFMA_Q(mh, nh) do { \
    __builtin_amdgcn_s_setprio(1); \
    _Pragma("unroll") for (int s2_ = 0; s2_ < 2; ++s2_) \
    _Pragma("unroll") for (int mi_ = 0; mi_ < 4; ++mi_) \
    _Pragma("unroll") for (int ni_ = 0; ni_ < 2; ++ni_) \
      acc[(mh) * 4 + mi_][(nh) * 2 + ni_] = __builtin_amdgcn_mfma_f32_16x16x32_bf16( \
          af[(mh) * 4 + mi_][s2_], bfr[(nh) * 2 + ni_][s2_], acc[(mh) * 4 + mi_][(nh) * 2 + ni_], 0, 0, 0); \
    __builtin_amdgcn_s_setprio(0); \
  } while (0)

#define PH_BAR() __builtin_amdgcn_s_barrier()
#define PH_LGKM() asm volatile("s_waitcnt lgkmcnt(0)" ::: "memory")

  // prologue: tiles 0 and 1 fully staged; drain tile 0 (oldest 8 loads); barrier
  for (int h = 0; h < 8; ++h) STAGE_H(h);
  asm volatile("s_waitcnt vmcnt(8)" ::: "memory");
  PH_BAR();

  // Per-phase ledger (1 barrier per phase; every read-phase drains its own
  // lgkm before MFMA, hence before its end barrier -> stage-vs-read safe):
  //  ph1: rd A03,B01(buf0); stage A0(t1)      ph2: rd B23(buf0); stage A1(t1)
  //  ph3: rd A47(buf0);     stage B0(t0+2)    ph4: stage B1(t0+2); vmcnt(4)
  //  ph5-8 mirror on buf1.  Drain points land full t1 (ph4) / t0+2 (ph8).
#pragma unroll 1
  for (int i = 0; i < 16; ++i) {
    const int hb = 8 * i;
    const bool more = (i < 15);
    // ph1
    READ_A03(0); READ_B01(0);
    if (i > 0) STAGE_H(hb + 4);
    PH_LGKM();
    MFMA_Q(0, 0);
    PH_BAR();
    // ph2
    READ_B23(0);
    if (i > 0) STAGE_H(hb + 5);
    PH_LGKM();
    MFMA_Q(0, 1);
    PH_BAR();
    // ph3
    READ_A47(0);
    if (more) STAGE_H(hb + 10);
    PH_LGKM();
    MFMA_Q(1, 0);
    PH_BAR();
    // ph4
    if (more) STAGE_H(hb + 11);
    MFMA_Q(1, 1);
    if (more) asm volatile("s_waitcnt vmcnt(4)" ::: "memory");
    else      asm volatile("s_waitcnt vmcnt(0)" ::: "memory");
    PH_BAR();
    // ph5
    READ_A03(1); READ_B01(1);
    if (more) STAGE_H(hb + 8);
    PH_LGKM();
    MFMA_Q(0, 0);
    PH_BAR();
    // ph6
    READ_B23(1);
    if (more) STAGE_H(hb + 9);
    PH_LGKM();
    MFMA_Q(0, 1);
    PH_BAR();
    // ph7
    READ_A47(1);
    if (more) STAGE_H(hb + 14);
    PH_LGKM();
    MFMA_Q(1, 0);
    PH_BAR();
    // ph8
    if (more) STAGE_H(hb + 15);
    MFMA_Q(1, 1);
    if (more) asm volatile("s_waitcnt vmcnt(4)" ::: "memory");
    else      asm volatile("s_waitcnt vmcnt(0)" ::: "memory");
    PH_BAR();
  }
#undef STAGE_H
#undef READ_A03
#undef READ_A47
#undef READ_B01
#undef READ_B23
#undef MFMA_Q
#undef PH_BAR
#undef PH_LGKM

  const int m0 = mt * 256, gcol0 = pt * 256;
  const int plmask = PL - 1;
  // pass 1: column softmax stats (no stores)
#pragma unroll
  for (int ni = 0; ni < 4; ++ni) {
    float lmax = -1e30f;
    float vv[8][4];
#pragma unroll
    for (int mi = 0; mi < 8; ++mi)
#pragma unroll
      for (int r = 0; r < 4; r++) {
        float x = bf2f(f2bf(acc[mi][ni][r]));
        vv[mi][r] = x;
        lmax = fmaxf(lmax, x);
      }
    float lsum = 0.f;
#pragma unroll
    for (int mi = 0; mi < 8; ++mi)
#pragma unroll
      for (int r = 0; r < 4; r++) lsum += __expf(vv[mi][r] - lmax);
#pragma unroll
    for (int d = 16; d <= 32; d <<= 1) {
      float omax = __shfl_xor(lmax, d, 64);
      float osum = __shfl_xor(lsum, d, 64);
      float nm = fmaxf(lmax, omax);
      lsum = lsum * __expf(lmax - nm) + osum * __expf(omax - nm);
      lmax = nm;
    }
    if (hi == 0) {
      const int part = mt * 2 + wr;
      const int g = gcol0 + wc * 64 + ni * 16 + lane;
      pmax[(size_t)part * GP + g] = lmax;
      psum[(size_t)part * GP + g] = lsum;
    }
  }
  // pass 2: C stores, same-line halves adjacent in time (L2 write-merge)
#pragma unroll
  for (int mi = 0; mi < 8; ++mi) {
#pragma unroll
    for (int r = 0; r < 4; r++) {
      const int mrow = m0 + wr * 128 + mi * 16 + hi * 4 + r;
#pragma unroll
      for (int ni = 0; ni < 4; ++ni) {
        const int g = gcol0 + wc * 64 + ni * 16 + fr;
        const int b = g >> plshift, pl = g & plmask;
        C[((size_t)b * NN + mrow) * PL + pl] = f2bf(acc[mi][ni][r]);
      }
    }
  }
}

// ---- cheb partials (col-softmax stats merged in): part[mc][b][j][pl] (bf16) ----
__global__ __launch_bounds__(256) void k_cheb(const unsigned short* __restrict__ S0c,
        const void* __restrict__ cheb, const unsigned short* __restrict__ cbf, int use_cbf,
        const float* __restrict__ xf, const float* __restrict__ pmax, const float* __restrict__ psum,
        unsigned short* __restrict__ part, int p0, int PL, int mspan, int GP) {
  const int b = blockIdx.z, mc = blockIdx.y;
  const int pl = blockIdx.x * 256 + threadIdx.x;
  const int n = p0 + pl;
  const int mode = get_mode(cheb);
  const int g = b * PL + pl;
  float mx = -1e30f;
#pragma unroll
  for (int c = 0; c < 16; c++) mx = fmaxf(mx, pmax[(size_t)c * GP + g]);
  float sm = 0.f;
#pragma unroll
  for (int c = 0; c < 16; c++) sm += psum[(size_t)c * GP + g] * __expf(pmax[(size_t)c * GP + g] - mx);
  const float inv = 1.f / sm;
  float acc[3][24];
#pragma unroll
  for (int k = 0; k < 3; k++)
#pragma unroll
    for (int j = 0; j < 24; j++) acc[k][j] = 0.f;
  const unsigned short* s0p = S0c + (size_t)b * NN * PL + pl;
  const int mEnd = mc * mspan + mspan;
  if (use_cbf || mode) {
    const unsigned short* cb = (use_cbf ? cbf : (const unsigned short*)cheb) + n;
#pragma unroll 2
    for (int m = mc * mspan; m < mEnd; ++m) {
      float w = __expf(bf2f(s0p[(size_t)m * PL]) - mx) * inv;
      const f32x4* xp = (const f32x4*)(xf + ((size_t)b * NN + m) * 24);
      float w0 = w * bf2f(cb[(size_t)m * NN]);
      float w1 = w * bf2f(cb[(size_t)NN * NN + (size_t)m * NN]);
      float w2 = w * bf2f(cb[(size_t)2 * NN * NN + (size_t)m * NN]);
#pragma unroll
      for (int q = 0; q < 6; q++) {
        f32x4 xv = xp[q];
#pragma unroll
        for (int e = 0; e < 4; e++) {
          int j = q * 4 + e;
          acc[0][j] += w0 * xv[e];
          acc[1][j] += w1 * xv[e];
          acc[2][j] += w2 * xv[e];
        }
      }
    }
  } else {
    const float* cb = (const float*)cheb + n;
#pragma unroll 2
    for (int m = mc * mspan; m < mEnd; ++m) {
      float w = __expf(bf2f(s0p[(size_t)m * PL]) - mx) * inv;
      const f32x4* xp = (const f32x4*)(xf + ((size_t)b * NN + m) * 24);
      float w0 = w * cb[(size_t)m * NN];
      float w1 = w * cb[(size_t)NN * NN + (size_t)m * NN];
      float w2 = w * cb[(size_t)2 * NN * NN + (size_t)m * NN];
#pragma unroll
      for (int q = 0; q < 6; q++) {
        f32x4 xv = xp[q];
#pragma unroll
        for (int e = 0; e < 4; e++) {
          int j = q * 4 + e;
          acc[0][j] += w0 * xv[e];
          acc[1][j] += w1 * xv[e];
          acc[2][j] += w2 * xv[e];
        }
      }
    }
  }
  unsigned short* pp = part + ((size_t)(mc * 8 + b) * 72) * PL + pl;
#pragma unroll
  for (int k = 0; k < 3; k++)
#pragma unroll
    for (int j = 0; j < 24; j++) pp[(size_t)(k * 24 + j) * PL] = f2bf(acc[k][j]);
}

__global__ void k_chebred(const unsigned short* __restrict__ part, float* __restrict__ rhsC,
                          int p0, int PL) {
  const int idx = blockIdx.x * 256 + threadIdx.x;
  if (idx >= 8 * 72 * PL) return;
  const int pl = idx % PL;
  const int r = idx / PL;
  const int j = r % 72, b = r / 72;
  float s = 0.f;
  for (int mc = 0; mc < MCV; ++mc)
    s += bf2f(part[((size_t)(mc * 8 + b) * 72 + j) * PL + pl]);
  rhsC[((size_t)b * NN + p0 + pl) * 72 + j] = s;
}

// ---- final: Theta mix + relu + tconv via MFMA + res(1x1) + relu + LN(64) ----
__global__ __launch_bounds__(256) void k_final(const float* __restrict__ rhsC,
      const float* __restrict__ Thf, const unsigned short* __restrict__ twr,
      const float* __restrict__ tbf, const float* __restrict__ rwf, const float* __restrict__ rbf,
      const float* __restrict__ lngf, const float* __restrict__ lnbf,
      const float* __restrict__ xf, void* __restrict__ out, const void* __restrict__ chebp) {
  const int mode = get_mode(chebp);
  __shared__ __align__(16) unsigned short ltw[192 * 72];
  __shared__ __align__(16) unsigned short gT[4][18][72];
  __shared__ float rl[4][72];
  __shared__ float prm[6][64];
  const int tid = threadIdx.x;
  const int wv = tid >> 6, lane = tid & 63;
  const size_t bn = (size_t)blockIdx.x * 4 + wv;

  for (int i = tid; i < 1536; i += 256) {
    const int row = i >> 3, cseg = (i & 7) * 8;
    *(bf16x8*)&ltw[row * 72 + cseg] = *(const bf16x8*)&twr[row * 64 + cseg];
  }
  if (tid < 64) {
    prm[0][tid] = tbf[tid] + rbf[tid];
    prm[1][tid] = rwf[tid * 2];
    prm[2][tid] = rwf[tid * 2 + 1];
    prm[3][tid] = lngf[tid];
    prm[4][tid] = lnbf[tid];
  }
  for (int i = lane; i < 648; i += 64) ((unsigned int*)&gT[wv][0][0])[i] = 0u;
  {
    const float* rp = rhsC + bn * 72;
    rl[wv][lane] = rp[lane];
    if (lane < 8) rl[wv][64 + lane] = rp[64 + lane];
  }
  __syncthreads();
  {
    const int c = lane;
    float th[6];
#pragma unroll
    for (int kf = 0; kf < 6; kf++) th[kf] = Thf[kf * 64 + c];
#pragma unroll
    for (int t = 0; t < 12; t++) {
      float s = 0.f;
#pragma unroll
      for (int kf = 0; kf < 6; kf++) s += rl[wv][kf * 12 + t] * th[kf];
      gT[wv][1 + t][c] = f2bf(fmaxf(s, 0.f));
    }
  }
  __syncthreads();
  const int fr = lane & 15, hi = lane >> 4;
  f32x4 acc4[4] = {};
#pragma unroll
  for (int dt = 0; dt < 3; dt++)
#pragma unroll
    for (int ks = 0; ks < 2; ks++) {
      bf16x8 bfrag = *(const bf16x8*)&gT[wv][fr + dt][ks * 32 + hi * 8];
#pragma unroll
      for (int ot = 0; ot < 4; ot++) {
        bf16x8 afrag = *(const bf16x8*)&ltw[(dt * 64 + ot * 16 + fr) * 72 + ks * 32 + hi * 8];
        acc4[ot] = __builtin_amdgcn_mfma_f32_16x16x32_bf16(afrag, bfrag, acc4[ot], 0, 0, 0);
      }
    }
  const int t = fr;
  const int tc = t < 12 ? t : 11;
  const float x0 = xf[bn * 24 + tc], x1 = xf[bn * 24 + 12 + tc];
  float vals[4][4];
  float sum = 0.f, sumsq = 0.f;
#pragma unroll
  for (int ot = 0; ot < 4; ot++) {
    f32x4 rbt4 = *(const f32x4*)&prm[0][ot * 16 + hi * 4];
    f32x4 rw04 = *(const f32x4*)&prm[1][ot * 16 + hi * 4];
    f32x4 rw14 = *(const f32x4*)&prm[2][ot * 16 + hi * 4];
#pragma unroll
    for (int r = 0; r < 4; r++) {
      float v = acc4[ot][r] + rbt4[r] + rw04[r] * x0 + rw14[r] * x1;
      v = fmaxf(v, 0.f);
      vals[ot][r] = v;
      sum += v; sumsq += v * v;
    }
  }
  sum   += __shfl_xor(sum, 16, 64);
  sumsq += __shfl_xor(sumsq, 16, 64);
  sum   += __shfl_xor(sum, 32, 64);
  sumsq += __shfl_xor(sumsq, 32, 64);
  const float mu = sum * (1.f / 64.f);
  const float var = sumsq * (1.f / 64.f) - mu * mu;
  const float rs = rsqrtf(var + 1e-5f);
  if (t < 12) {
#pragma unroll
    for (int ot = 0; ot < 4; ot++) {
      f32x4 lg4 = *(const f32x4*)&prm[3][ot * 16 + hi * 4];
      f32x4 lb4 = *(const f32x4*)&prm[4][ot * 16 + hi * 4];
#pragma unroll
      for (int r = 0; r < 4; r++) {
        const int o = ot * 16 + hi * 4 + r;
        float y = (vals[ot][r] - mu) * rs * lg4[r] + lb4[r];
        if (mode) ((unsigned short*)out)[bn * 768 + o * 12 + t] = f2bf(y);
        else      ((float*)out)[bn * 768 + o * 12 + t] = y;
      }
    }
  }
}

// ---------------- workspace plan ----------------
struct Plan {
  size_t o_xf, o_Th, o_U1, o_U2, o_U3, o_be, o_Ve, o_W1, o_W2, o_W3,
         o_twr, o_tb, o_rw, o_rb, o_lg, o_lb, o_Vs,
         o_E, o_lhs, o_rhsS, o_rhsC,
         o_R1, o_S0, o_pmax, o_psum, o_cbf;
  size_t total;
};

static Plan make_plan(int PL, int cbf) {
  Plan p; size_t off = 0;
  auto al = [&](size_t b) { size_t r = off; off += (b + 255) & ~(size_t)255; return r; };
  const int GP = 8 * PL;
  p.o_xf   = al((size_t)NB * NN * 24 * 4);
  p.o_Th   = al(384 * 4);
  p.o_U1   = al(2048 * 4);
  p.o_U2   = al(4096 * 4);
  p.o_U3   = al(2 * 4);
  p.o_be   = al(144 * 4);
  p.o_Ve   = al(144 * 4);
  p.o_W1   = al(12 * 4);
  p.o_W2   = al(24 * 4);
  p.o_W3   = al(2 * 4);
  p.o_twr  = al(12288 * 2);
  p.o_tb   = al(64 * 4);
  p.o_rw   = al(128 * 4);
  p.o_rb   = al(64 * 4);
  p.o_lg   = al(64 * 4);
  p.o_lb   = al(64 * 4);
  p.o_Vs   = al((size_t)NN * NN * 2);
  p.o_E    = al(NB * 144 * 4);
  p.o_lhs  = al((size_t)NB * NN * 12 * 4);
  p.o_rhsS = al((size_t)NB * 12 * NN * 4);
  p.o_rhsC = al((size_t)NB * NN * 72 * 4);
  // union region: sigT (32768*PL) aliased with bf16 part (MCV*8*72*2 = 36864*PL)
  p.o_R1   = al((size_t)36864 * PL);
  p.o_S0   = al((size_t)NB * NN * PL * 2);
  p.o_pmax = al((size_t)16 * GP * 4);
  p.o_psum = al((size_t)16 * GP * 4);
  p.o_cbf  = cbf ? al((size_t)3 * NN * NN * 2) : 0;
  p.total = off;
  return p;
}

extern "C" void kernel_launch(void* const* d_in, const int* in_sizes, int n_in,
                              void* d_out, int out_size, void* d_ws, size_t ws_size,
                              hipStream_t stream) {
  (void)in_sizes; (void)n_in; (void)out_size;
  char* ws = (char*)d_ws;

  int PL, use_cbf;
  if      (make_plan(1024, 1).total <= ws_size) { PL = 1024; use_cbf = 1; }
  else if (make_plan(1024, 0).total <= ws_size) { PL = 1024; use_cbf = 0; }
  else if (make_plan(512, 1).total  <= ws_size) { PL = 512;  use_cbf = 1; }
  else                                          { PL = 512;  use_cbf = 0; }
  const Plan P = make_plan(PL, use_cbf);
  const int GP = 8 * PL;
  const int plshift = (PL == 512) ? 9 : 10;
  const int mspan = NN / MCV;
  const void* chebp = d_in[1];

  float* xf   = (float*)(ws + P.o_xf);
  float* Ebuf = (float*)(ws + P.o_E);
  float* lhs  = (float*)(ws + P.o_lhs);
  float* rhsS = (float*)(ws + P.o_rhsS);
  float* rhsC = (float*)(ws + P.o_rhsC);
  unsigned short* sigT = (unsigned short*)(ws + P.o_R1);
  unsigned short* part = (unsigned short*)(ws + P.o_R1);
  unsigned short* S0c  = (unsigned short*)(ws + P.o_S0);
  float* pmax = (float*)(ws + P.o_pmax);
  float* psum = (float*)(ws + P.o_psum);
  unsigned short* cbfp = use_cbf ? (unsigned short*)(ws + P.o_cbf)
                                 : (unsigned short*)d_in[1];

  ConvArgs ca;
  auto seg = [&](int i, int di, size_t o, int count, int tobf) {
    ca.s[i].src = d_in[di]; ca.s[i].dst = (void*)(ws + o); ca.s[i].count = count; ca.s[i].tobf = tobf;
  };
  seg(0, 0, P.o_xf, 393216, 0);
  seg(1, 2, P.o_Th, 384, 0);
  seg(2, 3, P.o_U1, 2048, 0);
  seg(3, 4, P.o_U2, 4096, 0);
  seg(4, 5, P.o_U3, 2, 0);
  seg(5, 6, P.o_be, 144, 0);
  seg(6, 7, P.o_Ve, 144, 0);
  seg(7, 8, P.o_W1, 12, 0);
  seg(8, 9, P.o_W2, 24, 0);
  seg(9, 10, P.o_W3, 2, 0);
  seg(10, 14, P.o_tb, 64, 0);
  seg(11, 15, P.o_rw, 128, 0);
  seg(12, 16, P.o_rb, 64, 0);
  seg(13, 17, P.o_lg, 64, 0);
  seg(14, 18, P.o_lb, 64, 0);
  seg(15, 1, P.o_cbf, use_cbf ? 3 * NN * NN : 0, 1);
  k_convert<<<1024, 256, 0, stream>>>(ca, chebp);
  k_vsb<<<(NN * NN + 12288 + 255) / 256, 256, 0, stream>>>(d_in[12],
      (unsigned short*)(ws + P.o_Vs), d_in[13], (unsigned short*)(ws + P.o_twr), chebp);

  k_temp1<<<NB, 256, 0, stream>>>(xf, (float*)(ws + P.o_U1), (float*)(ws + P.o_U2),
                                  (float*)(ws + P.o_U3), (float*)(ws + P.o_be),
                                  (float*)(ws + P.o_Ve), Ebuf);
  k_xtat<<<dim3(8, NB), 256, 0, stream>>>(xf, Ebuf, (float*)(ws + P.o_W1), (float*)(ws + P.o_W2),
                                          (float*)(ws + P.o_W3), lhs, rhsS);

  const int nwg = 8 * (GP / 256);
  for (int p0 = 0; p0 < NN; p0 += PL) {
    k_sig<<<dim3(8, PL / 16), 256, 0, stream>>>(lhs, rhsS, d_in[11], sigT, chebp, p0, PL);
    k_gemm<<<nwg, 512, 0, stream>>>((unsigned short*)(ws + P.o_Vs), sigT, S0c,
                                    pmax, psum, PL, plshift, GP, nwg);
    k_cheb<<<dim3(PL / 256, MCV, NB), 256, 0, stream>>>(S0c, d_in[1], cbfp, use_cbf,
                                                        xf, pmax, psum, part, p0, PL, mspan, GP);
    k_chebred<<<(8 * 72 * PL + 255) / 256, 256, 0, stream>>>(part, rhsC, p0, PL);
  }

  k_final<<<NB * NN / 4, 256, 0, stream>>>(rhsC, (float*)(ws + P.o_Th),
      (unsigned short*)(ws + P.o_twr), (float*)(ws + P.o_tb), (float*)(ws + P.o_rw),
      (float*)(ws + P.o_rb), (float*)(ws + P.o_lg), (float*)(ws + P.o_lb), xf, d_out, chebp);
}